// Round 2
// baseline (1997.733 us; speedup 1.0000x reference)
//
#include <hip/hip_runtime.h>

#define BATCH 256
#define DIM 512
#define NACT 3
#define NMEM 25000
#define KNB 50
#define H1N 256
#define H2N 128
#define NSTEPS 5
#define KDELTA 0.001f

#define TB 128
#define TN 64
#define TKC 16

// ---------- row squared-norms (one wave per row) ----------
__global__ __launch_bounds__(256)
void rownorm_kernel(const float* __restrict__ rows, float* __restrict__ out, int nrows) {
    int wave = threadIdx.x >> 6, lane = threadIdx.x & 63;
    int r = blockIdx.x * 4 + wave;
    if (r >= nrows) return;
    const float* p = rows + (size_t)r * DIM;
    float4 v0 = *(const float4*)(p + lane * 8);
    float4 v1 = *(const float4*)(p + lane * 8 + 4);
    float s = v0.x*v0.x + v0.y*v0.y + v0.z*v0.z + v0.w*v0.w
            + v1.x*v1.x + v1.y*v1.y + v1.z*v1.z + v1.w*v1.w;
    for (int off = 32; off; off >>= 1) s += __shfl_down(s, off);
    if (lane == 0) out[r] = s;
}

// ---------- group batch rows by action for step j ----------
__global__ __launch_bounds__(256)
void group_kernel(const int* __restrict__ actions, int step,
                  int* __restrict__ perm, int* __restrict__ cnt) {
    __shared__ int lcnt[NACT];
    __shared__ int lperm[NACT * BATCH];
    int tid = threadIdx.x;
    if (tid < NACT) lcnt[tid] = 0;
    __syncthreads();
    int a = actions[tid * NSTEPS + step];
    int pos = atomicAdd(&lcnt[a], 1);
    lperm[a * BATCH + pos] = tid;
    __syncthreads();
    if (tid < NACT) cnt[tid] = lcnt[tid];
    for (int aa = 0; aa < NACT; ++aa) {
        int c = lcnt[aa];
        int f = (c > 0) ? lperm[aa * BATCH] : 0;   // pad with first member (benign dup writes)
        for (int i = c + tid; i < BATCH; i += 256) lperm[aa * BATCH + i] = f;
    }
    __syncthreads();
    for (int i = tid; i < NACT * BATCH; i += 256) perm[i] = lperm[i];
}

// ---------- distance GEMM: dist[b][n] = kn[a][n] - 2 * q_b . k_n  (qn added later) ----------
__global__ __launch_bounds__(256)
void dist_kernel(const float* __restrict__ emb, const float* __restrict__ keys,
                 const float* __restrict__ kn, const int* __restrict__ perm,
                 const int* __restrict__ cnt, float* __restrict__ dist) {
    int a = blockIdx.x >> 1;              // 2 b-tiles per action
    int tb0 = (blockIdx.x & 1) * TB;
    int c = cnt[a];
    if (tb0 >= c) return;
    int n0 = blockIdx.y * TN;

    __shared__ float Qs[TKC][TB];
    __shared__ float Ks[TKC][TN];
    __shared__ int rows[TB];

    int tid = threadIdx.x;
    if (tid < TB) {
        int i = tb0 + tid;
        rows[tid] = (i < c) ? perm[a * BATCH + i] : perm[a * BATCH];
    }
    __syncthreads();

    float acc[8][4] = {};
    int ty = tid >> 4, tx = tid & 15;
    const float* keysA = keys + (size_t)a * NMEM * DIM;

    for (int d0 = 0; d0 < DIM; d0 += TKC) {
        // Q chunk: 128 rows x 16 cols = 512 float4, 2 per thread
        #pragma unroll
        for (int it = 0; it < 2; ++it) {
            int idx = tid + it * 256;
            int r = idx >> 2, c4 = idx & 3;
            const float4 q4 = *(const float4*)(emb + (size_t)rows[r] * DIM + d0 + c4 * 4);
            Qs[c4*4+0][r] = q4.x; Qs[c4*4+1][r] = q4.y;
            Qs[c4*4+2][r] = q4.z; Qs[c4*4+3][r] = q4.w;
        }
        // K chunk: 64 rows x 16 cols = 256 float4, 1 per thread
        {
            int r = tid >> 2, c4 = tid & 3;
            int n = n0 + r;
            float4 k4 = make_float4(0.f, 0.f, 0.f, 0.f);
            if (n < NMEM) k4 = *(const float4*)(keysA + (size_t)n * DIM + d0 + c4 * 4);
            Ks[c4*4+0][r] = k4.x; Ks[c4*4+1][r] = k4.y;
            Ks[c4*4+2][r] = k4.z; Ks[c4*4+3][r] = k4.w;
        }
        __syncthreads();
        #pragma unroll
        for (int dk = 0; dk < TKC; ++dk) {
            float qv[8], kv[4];
            #pragma unroll
            for (int i = 0; i < 8; ++i) qv[i] = Qs[dk][ty * 8 + i];
            #pragma unroll
            for (int j = 0; j < 4; ++j) kv[j] = Ks[dk][tx * 4 + j];
            #pragma unroll
            for (int i = 0; i < 8; ++i)
                #pragma unroll
                for (int j = 0; j < 4; ++j)
                    acc[i][j] = fmaf(qv[i], kv[j], acc[i][j]);
        }
        __syncthreads();
    }
    #pragma unroll
    for (int j = 0; j < 4; ++j) {
        int n = n0 + tx * 4 + j;
        if (n >= NMEM) continue;
        float knv = kn[a * NMEM + n];
        #pragma unroll
        for (int i = 0; i < 8; ++i) {
            int b = rows[ty * 8 + i];
            dist[(size_t)b * NMEM + n] = knv - 2.0f * acc[i][j];
        }
    }
}

// ---------- exact top-50 radix select ----------
__device__ __forceinline__ unsigned flipf(float f) {
    unsigned u = __float_as_uint(f);
    return (u & 0x80000000u) ? ~u : (u | 0x80000000u);
}
__device__ __forceinline__ float unflipf(unsigned u) {
    return __uint_as_float((u & 0x80000000u) ? (u & 0x7FFFFFFFu) : ~u);
}

__device__ void find_bin(unsigned* hist, int per, unsigned target,
                         unsigned* segsum, unsigned* sh_bin, unsigned* sh_before) {
    int tid = threadIdx.x;
    unsigned s = 0;
    for (int i = 0; i < per; ++i) s += hist[tid * per + i];
    segsum[tid] = s;
    __syncthreads();
    if (tid == 0) {
        unsigned cum = 0; int seg = 0;
        while (cum + segsum[seg] < target) cum += segsum[seg++];
        int bin = seg * per;
        while (cum + hist[bin] < target) cum += hist[bin++];
        *sh_bin = (unsigned)bin; *sh_before = cum;
    }
    __syncthreads();
}

__global__ __launch_bounds__(256)
void topk_kernel(const float* __restrict__ dist, const float* __restrict__ qn,
                 int* __restrict__ idx_out, float* __restrict__ w_out) {
    __shared__ unsigned hist[2048];
    __shared__ unsigned segsum[256];
    __shared__ unsigned sh_bin, sh_before;
    __shared__ int sel[KNB];
    __shared__ float seld[KNB];
    __shared__ unsigned cnt_lt, cnt_eq;
    __shared__ int eqbuf[256];
    __shared__ float wsum_sh;

    int b = blockIdx.x, tid = threadIdx.x;
    const float* dr = dist + (size_t)b * NMEM;

    // pass 1: bits [31:21]
    for (int i = tid; i < 2048; i += 256) hist[i] = 0;
    __syncthreads();
    for (int n = tid; n < NMEM; n += 256) atomicAdd(&hist[flipf(dr[n]) >> 21], 1u);
    __syncthreads();
    find_bin(hist, 8, KNB, segsum, &sh_bin, &sh_before);
    unsigned P1 = sh_bin, cb1 = sh_before;
    __syncthreads();

    // pass 2: bits [20:10] within P1
    for (int i = tid; i < 2048; i += 256) hist[i] = 0;
    __syncthreads();
    for (int n = tid; n < NMEM; n += 256) {
        unsigned u = flipf(dr[n]);
        if ((u >> 21) == P1) atomicAdd(&hist[(u >> 10) & 0x7FFu], 1u);
    }
    __syncthreads();
    find_bin(hist, 8, KNB - cb1, segsum, &sh_bin, &sh_before);
    unsigned P2 = sh_bin, cb2 = cb1 + sh_before;
    __syncthreads();

    // pass 3: bits [9:0] within (P1,P2)
    for (int i = tid; i < 2048; i += 256) hist[i] = 0;
    __syncthreads();
    unsigned pfx = (P1 << 11) | P2;
    for (int n = tid; n < NMEM; n += 256) {
        unsigned u = flipf(dr[n]);
        if ((u >> 10) == pfx) atomicAdd(&hist[u & 0x3FFu], 1u);
    }
    __syncthreads();
    find_bin(hist, 4, KNB - cb2, segsum, &sh_bin, &sh_before);
    unsigned T = (pfx << 10) | sh_bin;
    __syncthreads();

    // collect
    if (tid == 0) { cnt_lt = 0; cnt_eq = 0; }
    __syncthreads();
    for (int n = tid; n < NMEM; n += 256) {
        float d = dr[n];
        unsigned u = flipf(d);
        if (u < T) { unsigned p = atomicAdd(&cnt_lt, 1u); sel[p] = n; seld[p] = d; }
        else if (u == T) { unsigned p = atomicAdd(&cnt_eq, 1u); if (p < 256) eqbuf[p] = n; }
    }
    __syncthreads();
    if (tid == 0) {
        int need = KNB - (int)cnt_lt;
        int m = (int)cnt_eq; if (m > 256) m = 256;
        float dT = unflipf(T);
        for (int k = 0; k < need; ++k) {   // smallest-index ties, matches lax.top_k
            int best = 0x7FFFFFFF, bi = 0;
            for (int i = 0; i < m; ++i) if (eqbuf[i] < best) { best = eqbuf[i]; bi = i; }
            eqbuf[bi] = 0x7FFFFFFF;
            sel[(int)cnt_lt + k] = best; seld[(int)cnt_lt + k] = dT;
        }
    }
    __syncthreads();
    float qnb = qn[b];
    if (tid < KNB) seld[tid] = 1.0f / (seld[tid] + qnb + KDELTA);
    __syncthreads();
    if (tid == 0) {
        float s = 0.f;
        for (int i = 0; i < KNB; ++i) s += seld[i];
        wsum_sh = s;
    }
    __syncthreads();
    if (tid < KNB) {
        w_out[b * KNB + tid] = seld[tid] / wsum_sh;
        idx_out[b * KNB + tid] = sel[tid];
    }
}

// ---------- gather: emb[b] = sum_k w * vals[a, idx_k]; fused next-qn ----------
__global__ __launch_bounds__(256)
void gather_kernel(const float* __restrict__ vals, const int* __restrict__ idx,
                   const float* __restrict__ w, const int* __restrict__ actions,
                   int step, float* __restrict__ emb_out, float* __restrict__ qn_out) {
    int b = blockIdx.x, tid = threadIdx.x;
    int a = actions[b * NSTEPS + step];
    __shared__ float wl[KNB];
    __shared__ int il[KNB];
    __shared__ float red[256];
    if (tid < KNB) { wl[tid] = w[b * KNB + tid]; il[tid] = idx[b * KNB + tid]; }
    __syncthreads();
    const float* va = vals + (size_t)a * NMEM * DIM;
    float acc0 = 0.f, acc1 = 0.f;
    for (int k = 0; k < KNB; ++k) {
        const float* vr = va + (size_t)il[k] * DIM;
        acc0 = fmaf(wl[k], vr[tid], acc0);
        acc1 = fmaf(wl[k], vr[tid + 256], acc1);
    }
    emb_out[b * DIM + tid] = acc0;
    emb_out[b * DIM + tid + 256] = acc1;
    red[tid] = acc0 * acc0 + acc1 * acc1;
    __syncthreads();
    for (int s = 128; s > 0; s >>= 1) { if (tid < s) red[tid] += red[tid + s]; __syncthreads(); }
    if (tid == 0) qn_out[b] = red[0];
}

// ---------- fused 3-layer MLP ----------
__global__ __launch_bounds__(256)
void predict_kernel(const float* __restrict__ emb, const float* __restrict__ w1,
                    const float* __restrict__ b1, const float* __restrict__ w2,
                    const float* __restrict__ b2, const float* __restrict__ w3,
                    const float* __restrict__ b3, float* __restrict__ out, int step) {
    int b = blockIdx.x, tid = threadIdx.x;
    __shared__ float xs[DIM];
    __shared__ float h1[H1N];
    __shared__ float h2[H2N];
    xs[tid] = emb[(size_t)b * DIM + tid];
    xs[tid + 256] = emb[(size_t)b * DIM + tid + 256];
    __syncthreads();
    float acc = b1[tid];
    #pragma unroll 8
    for (int d = 0; d < DIM; ++d) acc = fmaf(xs[d], w1[d * H1N + tid], acc);
    h1[tid] = acc > 0.f ? acc : expm1f(acc);
    __syncthreads();
    if (tid < H2N) {
        float a2 = b2[tid];
        #pragma unroll 8
        for (int d = 0; d < H1N; ++d) a2 = fmaf(h1[d], w2[d * H2N + tid], a2);
        h2[tid] = a2 > 0.f ? a2 : expm1f(a2);
    }
    __syncthreads();
    if (tid < 5) {
        float p = b3[tid];
        for (int d = 0; d < H2N; ++d) p = fmaf(h2[d], w3[d * 5 + tid], p);
        float o = p;
        if (tid == 1) o = 1.0f / (1.0f + expf(-p));
        out[b * (6 * 5) + step * 5 + tid] = o;
    }
}

extern "C" void kernel_launch(void* const* d_in, const int* in_sizes, int n_in,
                              void* d_out, int out_size, void* d_ws, size_t ws_size,
                              hipStream_t stream) {
    const float* x        = (const float*)d_in[0];
    const int*   actions  = (const int*)d_in[1];
    const float* mem_keys = (const float*)d_in[2];
    const float* mem_vals = (const float*)d_in[3];
    const float* w1 = (const float*)d_in[4];
    const float* b1 = (const float*)d_in[5];
    const float* w2 = (const float*)d_in[6];
    const float* b2 = (const float*)d_in[7];
    const float* w3 = (const float*)d_in[8];
    const float* b3 = (const float*)d_in[9];
    float* out = (float*)d_out;

    float* ws   = (float*)d_ws;
    float* kn   = ws;                       // 75008
    float* qnA  = kn + 75008;               // 256
    float* qnB  = qnA + 256;                // 256
    float* embA = qnB + 256;                // 131072
    float* embB = embA + 131072;            // 131072
    int*   perm = (int*)(embB + 131072);    // 768
    int*   cntb = perm + 768;               // 16
    int*   idxb = cntb + 16;                // 12800
    float* wb   = (float*)(idxb + 12800);   // 12800
    float* distb = wb + 12800;              // 6,400,000  (total ~27 MB)

    rownorm_kernel<<<dim3((NACT * NMEM + 3) / 4), dim3(256), 0, stream>>>(mem_keys, kn, NACT * NMEM);
    rownorm_kernel<<<dim3((BATCH + 3) / 4), dim3(256), 0, stream>>>(x, qnA, BATCH);
    predict_kernel<<<dim3(BATCH), dim3(256), 0, stream>>>(x, w1, b1, w2, b2, w3, b3, out, 0);

    const float* cur = x;
    float* qncur = qnA;
    for (int j = 0; j < NSTEPS; ++j) {
        group_kernel<<<dim3(1), dim3(256), 0, stream>>>(actions, j, perm, cntb);
        dist_kernel<<<dim3(NACT * 2, (NMEM + TN - 1) / TN), dim3(256), 0, stream>>>(
            cur, mem_keys, kn, perm, cntb, distb);
        topk_kernel<<<dim3(BATCH), dim3(256), 0, stream>>>(distb, qncur, idxb, wb);
        float* enext  = (j & 1) ? embB : embA;
        float* qnnext = (j & 1) ? qnA  : qnB;
        gather_kernel<<<dim3(BATCH), dim3(256), 0, stream>>>(mem_vals, idxb, wb, actions, j, enext, qnnext);
        predict_kernel<<<dim3(BATCH), dim3(256), 0, stream>>>(enext, w1, b1, w2, b2, w3, b3, out, j + 1);
        cur = enext; qncur = qnnext;
    }
}

// Round 4
// 1460.947 us; speedup vs baseline: 1.3674x; 1.3674x over previous
//
#include <hip/hip_runtime.h>

#define BATCH 256
#define DIM 512
#define NACT 3
#define NMEM 25000
#define KNB 50
#define KCAND 64
#define H1N 256
#define H2N 128
#define NSTEPS 5
#define KDELTA 0.001f

#define TB 128
#define TN 64
#define BK 64

typedef __attribute__((ext_vector_type(8))) short short8;
typedef __attribute__((ext_vector_type(4))) float f32x4;

// ---------- row squared-norms (one wave per row) ----------
__global__ __launch_bounds__(256)
void rownorm_kernel(const float* __restrict__ rows, float* __restrict__ out, int nrows) {
    int wave = threadIdx.x >> 6, lane = threadIdx.x & 63;
    int r = blockIdx.x * 4 + wave;
    if (r >= nrows) return;
    const float* p = rows + (size_t)r * DIM;
    float4 v0 = *(const float4*)(p + lane * 8);
    float4 v1 = *(const float4*)(p + lane * 8 + 4);
    float s = v0.x*v0.x + v0.y*v0.y + v0.z*v0.z + v0.w*v0.w
            + v1.x*v1.x + v1.y*v1.y + v1.z*v1.z + v1.w*v1.w;
    for (int off = 32; off; off >>= 1) s += __shfl_down(s, off);
    if (lane == 0) out[r] = s;
}

// ---------- group batch rows by action for step j ----------
__global__ __launch_bounds__(256)
void group_kernel(const int* __restrict__ actions, int step,
                  int* __restrict__ perm, int* __restrict__ cnt) {
    __shared__ int lcnt[NACT];
    __shared__ int lperm[NACT * BATCH];
    int tid = threadIdx.x;
    if (tid < NACT) lcnt[tid] = 0;
    __syncthreads();
    int a = actions[tid * NSTEPS + step];
    int pos = atomicAdd(&lcnt[a], 1);
    lperm[a * BATCH + pos] = tid;
    __syncthreads();
    if (tid < NACT) cnt[tid] = lcnt[tid];
    for (int aa = 0; aa < NACT; ++aa) {
        int c = lcnt[aa];
        int f = (c > 0) ? lperm[aa * BATCH] : 0;
        for (int i = c + tid; i < BATCH; i += 256) lperm[aa * BATCH + i] = f;
    }
    __syncthreads();
    for (int i = tid; i < NACT * BATCH; i += 256) perm[i] = lperm[i];
}

// ---------- split-bf16 helpers ----------
__device__ __forceinline__ unsigned short bf16rn(float f) {
    unsigned u = __float_as_uint(f);
    u += 0x7FFFu + ((u >> 16) & 1u);
    return (unsigned short)(u >> 16);
}

// ---------- approx distance GEMM via 3-pass split-bf16 MFMA ----------
// dist[b][n] = kn[a][n] - 2 * q_b . k_n   (qn constant per row: irrelevant for ranking)
__global__ __launch_bounds__(256)
void dist_kernel(const float* __restrict__ emb, const float* __restrict__ keys,
                 const float* __restrict__ kn, const int* __restrict__ perm,
                 const int* __restrict__ cnt, float* __restrict__ dist) {
    int a = blockIdx.x >> 1;
    int tb0 = (blockIdx.x & 1) * TB;
    int c = cnt[a];
    if (tb0 >= c) return;
    int n0 = blockIdx.y * TN;

    __shared__ __align__(16) unsigned short Qh[TB][BK], Ql[TB][BK];
    __shared__ __align__(16) unsigned short Kh[TN][BK], Kl[TN][BK];
    __shared__ int rows[TB];

    int tid = threadIdx.x;
    if (tid < TB) {
        int i = tb0 + tid;
        rows[tid] = perm[a * BATCH + (i < c ? i : 0)];
    }
    __syncthreads();

    int lane = tid & 63, wave = tid >> 6;
    int wm = wave >> 1, wn = wave & 1;

    f32x4 acc[4][2] = {};

    int qr = tid >> 1, qkc = (tid & 1) * 32;
    int kr = tid >> 2, kkc = (tid & 3) * 16;
    const float* keysA = keys + (size_t)a * NMEM * DIM;
    bool kvalid = (n0 + kr) < NMEM;
    const float* qsrc = emb + (size_t)rows[qr] * DIM + qkc;
    const float* ksrc = keysA + (size_t)(n0 + kr) * DIM + kkc;

    for (int d0 = 0; d0 < DIM; d0 += BK) {
        {
            int swz = (qr & 7) * 8;
            #pragma unroll
            for (int j = 0; j < 4; ++j) {
                float4 v0 = *(const float4*)(qsrc + d0 + j * 8);
                float4 v1 = *(const float4*)(qsrc + d0 + j * 8 + 4);
                float f[8] = {v0.x, v0.y, v0.z, v0.w, v1.x, v1.y, v1.z, v1.w};
                short8 hv, lv;
                #pragma unroll
                for (int i = 0; i < 8; ++i) {
                    unsigned short hh = bf16rn(f[i]);
                    hv[i] = (short)hh;
                    lv[i] = (short)bf16rn(f[i] - __uint_as_float((unsigned)hh << 16));
                }
                int col = (qkc + j * 8) ^ swz;
                *(short8*)&Qh[qr][col] = hv;
                *(short8*)&Ql[qr][col] = lv;
            }
        }
        {
            int swz = (kr & 7) * 8;
            #pragma unroll
            for (int j = 0; j < 2; ++j) {
                float4 v0 = kvalid ? *(const float4*)(ksrc + d0 + j * 8)
                                   : make_float4(0.f, 0.f, 0.f, 0.f);
                float4 v1 = kvalid ? *(const float4*)(ksrc + d0 + j * 8 + 4)
                                   : make_float4(0.f, 0.f, 0.f, 0.f);
                float f[8] = {v0.x, v0.y, v0.z, v0.w, v1.x, v1.y, v1.z, v1.w};
                short8 hv, lv;
                #pragma unroll
                for (int i = 0; i < 8; ++i) {
                    unsigned short hh = bf16rn(f[i]);
                    hv[i] = (short)hh;
                    lv[i] = (short)bf16rn(f[i] - __uint_as_float((unsigned)hh << 16));
                }
                int col = (kkc + j * 8) ^ swz;
                *(short8*)&Kh[kr][col] = hv;
                *(short8*)&Kl[kr][col] = lv;
            }
        }
        __syncthreads();
        #pragma unroll
        for (int kk = 0; kk < BK; kk += 32) {
            int kcol = kk + (lane >> 4) * 8;
            short8 ah[4], al[4], bh[2], bl[2];
            #pragma unroll
            for (int mf = 0; mf < 4; ++mf) {
                int m = wm * 64 + mf * 16 + (lane & 15);
                int cc = kcol ^ ((m & 7) * 8);
                ah[mf] = *(const short8*)&Qh[m][cc];
                al[mf] = *(const short8*)&Ql[m][cc];
            }
            #pragma unroll
            for (int nf = 0; nf < 2; ++nf) {
                int n = wn * 32 + nf * 16 + (lane & 15);
                int cc = kcol ^ ((n & 7) * 8);
                bh[nf] = *(const short8*)&Kh[n][cc];
                bl[nf] = *(const short8*)&Kl[n][cc];
            }
            #pragma unroll
            for (int mf = 0; mf < 4; ++mf)
                #pragma unroll
                for (int nf = 0; nf < 2; ++nf) {
                    acc[mf][nf] = __builtin_amdgcn_mfma_f32_16x16x32_bf16(ah[mf], bh[nf], acc[mf][nf], 0, 0, 0);
                    acc[mf][nf] = __builtin_amdgcn_mfma_f32_16x16x32_bf16(ah[mf], bl[nf], acc[mf][nf], 0, 0, 0);
                    acc[mf][nf] = __builtin_amdgcn_mfma_f32_16x16x32_bf16(al[mf], bh[nf], acc[mf][nf], 0, 0, 0);
                }
        }
        __syncthreads();
    }

    #pragma unroll
    for (int nf = 0; nf < 2; ++nf) {
        int n = n0 + wn * 32 + nf * 16 + (lane & 15);
        if (n >= NMEM) continue;
        float knv = kn[a * NMEM + n];
        #pragma unroll
        for (int mf = 0; mf < 4; ++mf) {
            #pragma unroll
            for (int r = 0; r < 4; ++r) {
                int m = wm * 64 + mf * 16 + (lane >> 4) * 4 + r;
                int b = rows[m];
                dist[(size_t)b * NMEM + n] = knv - 2.0f * acc[mf][nf][r];
            }
        }
    }
}

// ---------- radix select: top-64 candidate indices per row ----------
__device__ __forceinline__ unsigned flipf(float f) {
    unsigned u = __float_as_uint(f);
    return (u & 0x80000000u) ? ~u : (u | 0x80000000u);
}

__device__ void find_bin(unsigned* hist, int per, unsigned target,
                         unsigned* segsum, unsigned* sh_bin, unsigned* sh_before) {
    int tid = threadIdx.x;
    unsigned s = 0;
    for (int i = 0; i < per; ++i) s += hist[tid * per + i];
    segsum[tid] = s;
    __syncthreads();
    if (tid == 0) {
        unsigned cum = 0; int seg = 0;
        while (cum + segsum[seg] < target) cum += segsum[seg++];
        int bin = seg * per;
        while (cum + hist[bin] < target) cum += hist[bin++];
        *sh_bin = (unsigned)bin; *sh_before = cum;
    }
    __syncthreads();
}

__global__ __launch_bounds__(256)
void cand_kernel(const float* __restrict__ dist, int* __restrict__ cand_out) {
    __shared__ unsigned hist[2048];
    __shared__ unsigned segsum[256];
    __shared__ unsigned sh_bin, sh_before;
    __shared__ int sel[KCAND];
    __shared__ unsigned cnt_lt, cnt_eq;
    __shared__ int eqbuf[256];

    int b = blockIdx.x, tid = threadIdx.x;
    const float* dr = dist + (size_t)b * NMEM;

    for (int i = tid; i < 2048; i += 256) hist[i] = 0;
    __syncthreads();
    for (int n = tid; n < NMEM; n += 256) atomicAdd(&hist[flipf(dr[n]) >> 21], 1u);
    __syncthreads();
    find_bin(hist, 8, KCAND, segsum, &sh_bin, &sh_before);
    unsigned P1 = sh_bin, cb1 = sh_before;
    __syncthreads();

    for (int i = tid; i < 2048; i += 256) hist[i] = 0;
    __syncthreads();
    for (int n = tid; n < NMEM; n += 256) {
        unsigned u = flipf(dr[n]);
        if ((u >> 21) == P1) atomicAdd(&hist[(u >> 10) & 0x7FFu], 1u);
    }
    __syncthreads();
    find_bin(hist, 8, KCAND - cb1, segsum, &sh_bin, &sh_before);
    unsigned P2 = sh_bin, cb2 = cb1 + sh_before;
    __syncthreads();

    for (int i = tid; i < 2048; i += 256) hist[i] = 0;
    __syncthreads();
    unsigned pfx = (P1 << 11) | P2;
    for (int n = tid; n < NMEM; n += 256) {
        unsigned u = flipf(dr[n]);
        if ((u >> 10) == pfx) atomicAdd(&hist[u & 0x3FFu], 1u);
    }
    __syncthreads();
    find_bin(hist, 4, KCAND - cb2, segsum, &sh_bin, &sh_before);
    unsigned T = (pfx << 10) | sh_bin;
    __syncthreads();

    if (tid == 0) { cnt_lt = 0; cnt_eq = 0; }
    __syncthreads();
    for (int n = tid; n < NMEM; n += 256) {
        unsigned u = flipf(dr[n]);
        if (u < T) { unsigned p = atomicAdd(&cnt_lt, 1u); sel[p] = n; }
        else if (u == T) { unsigned p = atomicAdd(&cnt_eq, 1u); if (p < 256) eqbuf[p] = n; }
    }
    __syncthreads();
    if (tid == 0) {
        int need = KCAND - (int)cnt_lt;
        int m = (int)cnt_eq; if (m > 256) m = 256;
        for (int k = 0; k < need; ++k) {
            int best = 0x7FFFFFFF, bi = 0;
            for (int i = 0; i < m; ++i) if (eqbuf[i] < best) { best = eqbuf[i]; bi = i; }
            eqbuf[bi] = 0x7FFFFFFF;
            sel[(int)cnt_lt + k] = best;
        }
    }
    __syncthreads();
    if (tid < KCAND) cand_out[b * KCAND + tid] = sel[tid];
}

// ---------- exact f32 refine: 64 candidates -> exact top-50 + weights ----------
__global__ __launch_bounds__(256)
void refine_kernel(const float* __restrict__ emb, const float* __restrict__ keys,
                   const float* __restrict__ kn, const float* __restrict__ qn,
                   const int* __restrict__ actions, int step,
                   const int* __restrict__ cand,
                   int* __restrict__ idx_out, float* __restrict__ w_out) {
    int b = blockIdx.x, tid = threadIdx.x;
    int a = actions[b * NSTEPS + step];
    int c = tid & 63, p = tid >> 6;
    __shared__ float qs[DIM];
    __shared__ float part[4][64];
    __shared__ float dsh[64];
    __shared__ int   nsh[64];
    __shared__ float wsel[KNB];
    __shared__ int   isel[KNB];
    __shared__ float wsum_sh;

    qs[tid] = emb[(size_t)b * DIM + tid];
    qs[tid + 256] = emb[(size_t)b * DIM + tid + 256];
    int n = cand[b * KCAND + c];
    if (p == 0) nsh[c] = n;
    __syncthreads();

    const float* krow = keys + ((size_t)a * NMEM + n) * DIM + p * 128;
    const float* qp = qs + p * 128;
    float s = 0.f;
    #pragma unroll
    for (int i = 0; i < 128; i += 4) {
        float4 kv = *(const float4*)(krow + i);
        s = fmaf(kv.x, qp[i+0], s);
        s = fmaf(kv.y, qp[i+1], s);
        s = fmaf(kv.z, qp[i+2], s);
        s = fmaf(kv.w, qp[i+3], s);
    }
    part[p][c] = s;
    __syncthreads();
    if (tid < 64) {
        float dot = part[0][tid] + part[1][tid] + part[2][tid] + part[3][tid];
        dsh[tid] = qn[b] + kn[a * NMEM + nsh[tid]] - 2.0f * dot;
    }
    __syncthreads();
    if (tid < 64) {
        float di = dsh[tid]; int ni = nsh[tid];
        int rank = 0;
        for (int j = 0; j < 64; ++j) {
            float dj = dsh[j];
            rank += (dj < di || (dj == di && nsh[j] < ni)) ? 1 : 0;
        }
        if (rank < KNB) { wsel[rank] = 1.0f / (di + KDELTA); isel[rank] = ni; }
    }
    __syncthreads();
    if (tid == 0) {
        float ssum = 0.f;
        for (int i = 0; i < KNB; ++i) ssum += wsel[i];
        wsum_sh = ssum;
    }
    __syncthreads();
    if (tid < KNB) {
        w_out[b * KNB + tid] = wsel[tid] / wsum_sh;
        idx_out[b * KNB + tid] = isel[tid];
    }
}

// ---------- gather: emb[b] = sum_k w * vals[a, idx_k]; fused next-qn ----------
__global__ __launch_bounds__(256)
void gather_kernel(const float* __restrict__ vals, const int* __restrict__ idx,
                   const float* __restrict__ w, const int* __restrict__ actions,
                   int step, float* __restrict__ emb_out, float* __restrict__ qn_out) {
    int b = blockIdx.x, tid = threadIdx.x;
    int a = actions[b * NSTEPS + step];
    __shared__ float wl[KNB];
    __shared__ int il[KNB];
    __shared__ float red[256];
    if (tid < KNB) { wl[tid] = w[b * KNB + tid]; il[tid] = idx[b * KNB + tid]; }
    __syncthreads();
    const float* va = vals + (size_t)a * NMEM * DIM;
    float acc0 = 0.f, acc1 = 0.f;
    for (int k = 0; k < KNB; ++k) {
        const float* vr = va + (size_t)il[k] * DIM;
        acc0 = fmaf(wl[k], vr[tid], acc0);
        acc1 = fmaf(wl[k], vr[tid + 256], acc1);
    }
    emb_out[b * DIM + tid] = acc0;
    emb_out[b * DIM + tid + 256] = acc1;
    red[tid] = acc0 * acc0 + acc1 * acc1;
    __syncthreads();
    for (int s = 128; s > 0; s >>= 1) { if (tid < s) red[tid] += red[tid + s]; __syncthreads(); }
    if (tid == 0) qn_out[b] = red[0];
}

// ---------- fused 3-layer MLP ----------
__global__ __launch_bounds__(256)
void predict_kernel(const float* __restrict__ emb, const float* __restrict__ w1,
                    const float* __restrict__ b1, const float* __restrict__ w2,
                    const float* __restrict__ b2, const float* __restrict__ w3,
                    const float* __restrict__ b3, float* __restrict__ out, int step) {
    int b = blockIdx.x, tid = threadIdx.x;
    __shared__ float xs[DIM];
    __shared__ float h1[H1N];
    __shared__ float h2[H2N];
    xs[tid] = emb[(size_t)b * DIM + tid];
    xs[tid + 256] = emb[(size_t)b * DIM + tid + 256];
    __syncthreads();
    float acc = b1[tid];
    #pragma unroll 8
    for (int d = 0; d < DIM; ++d) acc = fmaf(xs[d], w1[d * H1N + tid], acc);
    h1[tid] = acc > 0.f ? acc : expm1f(acc);
    __syncthreads();
    if (tid < H2N) {
        float a2 = b2[tid];
        #pragma unroll 8
        for (int d = 0; d < H1N; ++d) a2 = fmaf(h1[d], w2[d * H2N + tid], a2);
        h2[tid] = a2 > 0.f ? a2 : expm1f(a2);
    }
    __syncthreads();
    if (tid < 5) {
        float p = b3[tid];
        for (int d = 0; d < H2N; ++d) p = fmaf(h2[d], w3[d * 5 + tid], p);
        float o = p;
        if (tid == 1) o = 1.0f / (1.0f + expf(-p));
        out[b * (6 * 5) + step * 5 + tid] = o;
    }
}

extern "C" void kernel_launch(void* const* d_in, const int* in_sizes, int n_in,
                              void* d_out, int out_size, void* d_ws, size_t ws_size,
                              hipStream_t stream) {
    const float* x        = (const float*)d_in[0];
    const int*   actions  = (const int*)d_in[1];
    const float* mem_keys = (const float*)d_in[2];
    const float* mem_vals = (const float*)d_in[3];
    const float* w1 = (const float*)d_in[4];
    const float* b1 = (const float*)d_in[5];
    const float* w2 = (const float*)d_in[6];
    const float* b2 = (const float*)d_in[7];
    const float* w3 = (const float*)d_in[8];
    const float* b3 = (const float*)d_in[9];
    float* out = (float*)d_out;

    float* ws   = (float*)d_ws;
    float* kn   = ws;                        // 75008
    float* qnA  = kn + 75008;                // 256
    float* qnB  = qnA + 256;                 // 256
    float* embA = qnB + 256;                 // 131072
    float* embB = embA + 131072;             // 131072
    int*   perm = (int*)(embB + 131072);     // 768
    int*   cntb = perm + 768;                // 16
    int*   candb = cntb + 16;                // 16384
    int*   idxb = candb + BATCH * KCAND;     // 12800
    float* wb   = (float*)(idxb + 12800);    // 12800
    float* distb = wb + 12800;               // 6,400,000  (total ~27 MB)

    rownorm_kernel<<<dim3((NACT * NMEM + 3) / 4), dim3(256), 0, stream>>>(mem_keys, kn, NACT * NMEM);
    rownorm_kernel<<<dim3((BATCH + 3) / 4), dim3(256), 0, stream>>>(x, qnA, BATCH);
    predict_kernel<<<dim3(BATCH), dim3(256), 0, stream>>>(x, w1, b1, w2, b2, w3, b3, out, 0);

    const float* cur = x;
    float* qncur = qnA;
    for (int j = 0; j < NSTEPS; ++j) {
        group_kernel<<<dim3(1), dim3(256), 0, stream>>>(actions, j, perm, cntb);
        dist_kernel<<<dim3(NACT * 2, (NMEM + TN - 1) / TN), dim3(256), 0, stream>>>(
            cur, mem_keys, kn, perm, cntb, distb);
        cand_kernel<<<dim3(BATCH), dim3(256), 0, stream>>>(distb, candb);
        refine_kernel<<<dim3(BATCH), dim3(256), 0, stream>>>(
            cur, mem_keys, kn, qncur, actions, j, candb, idxb, wb);
        float* enext  = (j & 1) ? embB : embA;
        float* qnnext = (j & 1) ? qnA  : qnB;
        gather_kernel<<<dim3(BATCH), dim3(256), 0, stream>>>(mem_vals, idxb, wb, actions, j, enext, qnnext);
        predict_kernel<<<dim3(BATCH), dim3(256), 0, stream>>>(enext, w1, b1, w2, b2, w3, b3, out, j + 1);
        cur = enext; qncur = qnnext;
    }
}

// Round 5
// 1356.158 us; speedup vs baseline: 1.4731x; 1.0773x over previous
//
#include <hip/hip_runtime.h>

#define BATCH 256
#define DIM 512
#define NACT 3
#define NMEM 25000
#define KNB 50
#define KCAND 128
#define H1N 256
#define H2N 128
#define NSTEPS 5
#define KDELTA 0.001f

#define TB 128
#define TN 128
#define BK 64

typedef __attribute__((ext_vector_type(8))) short short8;
typedef __attribute__((ext_vector_type(4))) float f32x4;

// ---------- row squared-norms (one wave per row) ----------
__global__ __launch_bounds__(256)
void rownorm_kernel(const float* __restrict__ rows, float* __restrict__ out, int nrows) {
    int wave = threadIdx.x >> 6, lane = threadIdx.x & 63;
    int r = blockIdx.x * 4 + wave;
    if (r >= nrows) return;
    const float* p = rows + (size_t)r * DIM;
    float4 v0 = *(const float4*)(p + lane * 8);
    float4 v1 = *(const float4*)(p + lane * 8 + 4);
    float s = v0.x*v0.x + v0.y*v0.y + v0.z*v0.z + v0.w*v0.w
            + v1.x*v1.x + v1.y*v1.y + v1.z*v1.z + v1.w*v1.w;
    for (int off = 32; off; off >>= 1) s += __shfl_down(s, off);
    if (lane == 0) out[r] = s;
}

// ---------- group batch rows by action, all steps in one launch ----------
__global__ __launch_bounds__(256)
void group_all_kernel(const int* __restrict__ actions,
                      int* __restrict__ perm, int* __restrict__ cnt) {
    int step = blockIdx.x;
    __shared__ int lcnt[NACT];
    __shared__ int lperm[NACT * BATCH];
    int tid = threadIdx.x;
    if (tid < NACT) lcnt[tid] = 0;
    __syncthreads();
    int a = actions[tid * NSTEPS + step];
    int pos = atomicAdd(&lcnt[a], 1);
    lperm[a * BATCH + pos] = tid;
    __syncthreads();
    if (tid < NACT) cnt[step * 4 + tid] = lcnt[tid];
    for (int aa = 0; aa < NACT; ++aa) {
        int c = lcnt[aa];
        int f = (c > 0) ? lperm[aa * BATCH] : 0;
        for (int i = c + tid; i < BATCH; i += 256) lperm[aa * BATCH + i] = f;
    }
    __syncthreads();
    for (int i = tid; i < NACT * BATCH; i += 256)
        perm[step * NACT * BATCH + i] = lperm[i];
}

__device__ __forceinline__ unsigned short bf16rn(float f) {
    unsigned u = __float_as_uint(f);
    u += 0x7FFFu + ((u >> 16) & 1u);
    return (unsigned short)(u >> 16);
}

// ---------- approx distance GEMM: single-pass bf16 MFMA, 128x128 tile ----------
// dist[b][n] ~= kn[a][n] - 2 * q_b . k_n   (qn constant per row: irrelevant for ranking)
__global__ __launch_bounds__(256)
void dist_kernel(const float* __restrict__ emb, const float* __restrict__ keys,
                 const float* __restrict__ kn, const int* __restrict__ perm,
                 const int* __restrict__ cnt, float* __restrict__ dist) {
    int a = blockIdx.x >> 1;
    int tb0 = (blockIdx.x & 1) * TB;
    int c = cnt[a];
    if (tb0 >= c) return;
    int n0 = blockIdx.y * TN;

    __shared__ __align__(16) unsigned short Qh[TB][BK];
    __shared__ __align__(16) unsigned short Kh[TN][BK];
    __shared__ int rows[TB];

    int tid = threadIdx.x;
    if (tid < TB) {
        int i = tb0 + tid;
        rows[tid] = perm[a * BATCH + (i < c ? i : 0)];
    }
    __syncthreads();

    int lane = tid & 63, wave = tid >> 6;
    int wm = wave >> 1, wn = wave & 1;

    f32x4 acc[4][4] = {};

    int sr = tid >> 1, sc = (tid & 1) * 32;    // staging: row, 32-float col block
    int swz = (sr & 7) * 8;
    const float* keysA = keys + (size_t)a * NMEM * DIM;
    bool kvalid = (n0 + sr) < NMEM;
    const float* qsrc = emb + (size_t)rows[sr] * DIM + sc;
    const float* ksrc = keysA + (size_t)(n0 + sr) * DIM + sc;

    for (int d0 = 0; d0 < DIM; d0 += BK) {
        #pragma unroll
        for (int j = 0; j < 4; ++j) {
            float4 v0 = *(const float4*)(qsrc + d0 + j * 8);
            float4 v1 = *(const float4*)(qsrc + d0 + j * 8 + 4);
            float f[8] = {v0.x, v0.y, v0.z, v0.w, v1.x, v1.y, v1.z, v1.w};
            short8 hv;
            #pragma unroll
            for (int i = 0; i < 8; ++i) hv[i] = (short)bf16rn(f[i]);
            *(short8*)&Qh[sr][(sc + j * 8) ^ swz] = hv;
        }
        #pragma unroll
        for (int j = 0; j < 4; ++j) {
            float4 v0 = kvalid ? *(const float4*)(ksrc + d0 + j * 8)
                               : make_float4(0.f, 0.f, 0.f, 0.f);
            float4 v1 = kvalid ? *(const float4*)(ksrc + d0 + j * 8 + 4)
                               : make_float4(0.f, 0.f, 0.f, 0.f);
            float f[8] = {v0.x, v0.y, v0.z, v0.w, v1.x, v1.y, v1.z, v1.w};
            short8 hv;
            #pragma unroll
            for (int i = 0; i < 8; ++i) hv[i] = (short)bf16rn(f[i]);
            *(short8*)&Kh[sr][(sc + j * 8) ^ swz] = hv;
        }
        __syncthreads();
        #pragma unroll
        for (int kk = 0; kk < BK; kk += 32) {
            int kcol = kk + (lane >> 4) * 8;
            short8 av[4], bv[4];
            #pragma unroll
            for (int mf = 0; mf < 4; ++mf) {
                int m = wm * 64 + mf * 16 + (lane & 15);
                av[mf] = *(const short8*)&Qh[m][kcol ^ ((m & 7) * 8)];
            }
            #pragma unroll
            for (int nf = 0; nf < 4; ++nf) {
                int n = wn * 64 + nf * 16 + (lane & 15);
                bv[nf] = *(const short8*)&Kh[n][kcol ^ ((n & 7) * 8)];
            }
            #pragma unroll
            for (int mf = 0; mf < 4; ++mf)
                #pragma unroll
                for (int nf = 0; nf < 4; ++nf)
                    acc[mf][nf] = __builtin_amdgcn_mfma_f32_16x16x32_bf16(av[mf], bv[nf], acc[mf][nf], 0, 0, 0);
        }
        __syncthreads();
    }

    // C/D layout: col=lane&15, row=(lane>>4)*4+reg
    #pragma unroll
    for (int nf = 0; nf < 4; ++nf) {
        int n = n0 + wn * 64 + nf * 16 + (lane & 15);
        if (n >= NMEM) continue;
        float knv = kn[a * NMEM + n];
        #pragma unroll
        for (int mf = 0; mf < 4; ++mf) {
            #pragma unroll
            for (int r = 0; r < 4; ++r) {
                int m = wm * 64 + mf * 16 + (lane >> 4) * 4 + r;
                int b = rows[m];
                dist[(size_t)b * NMEM + n] = knv - 2.0f * acc[mf][nf][r];
            }
        }
    }
}

// ---------- fused select: radix top-128 candidates + exact f32 refine ----------
__device__ __forceinline__ unsigned flipf(float f) {
    unsigned u = __float_as_uint(f);
    return (u & 0x80000000u) ? ~u : (u | 0x80000000u);
}

__device__ void find_bin(unsigned* hist, int per, unsigned target,
                         unsigned* segsum, unsigned* sh_bin, unsigned* sh_before) {
    int tid = threadIdx.x;
    unsigned s = 0;
    for (int i = 0; i < per; ++i) s += hist[tid * per + i];
    segsum[tid] = s;
    __syncthreads();
    if (tid == 0) {
        unsigned cum = 0; int seg = 0;
        while (cum + segsum[seg] < target) cum += segsum[seg++];
        int bin = seg * per;
        while (cum + hist[bin] < target) cum += hist[bin++];
        *sh_bin = (unsigned)bin; *sh_before = cum;
    }
    __syncthreads();
}

__global__ __launch_bounds__(256)
void select_kernel(const float* __restrict__ dist, const float* __restrict__ emb,
                   const float* __restrict__ keys, const float* __restrict__ kn,
                   const float* __restrict__ qn, const int* __restrict__ actions,
                   int step, int* __restrict__ idx_out, float* __restrict__ w_out) {
    __shared__ unsigned hist[2048];
    __shared__ unsigned segsum[256];
    __shared__ unsigned sh_bin, sh_before;
    __shared__ int sel[KCAND];
    __shared__ unsigned cnt_lt, cnt_eq;
    __shared__ int eqbuf[256];
    __shared__ float qs[DIM];
    __shared__ float part[256];
    __shared__ float dsh[KCAND];
    __shared__ float wsel[KNB];
    __shared__ int   isel[KNB];
    __shared__ float wsum_sh;

    int b = blockIdx.x, tid = threadIdx.x;
    const float* dr = dist + (size_t)b * NMEM;

    qs[tid] = emb[(size_t)b * DIM + tid];
    qs[tid + 256] = emb[(size_t)b * DIM + tid + 256];

    // pass 1: bits [31:21]
    for (int i = tid; i < 2048; i += 256) hist[i] = 0;
    __syncthreads();
    for (int n = tid; n < NMEM; n += 256) atomicAdd(&hist[flipf(dr[n]) >> 21], 1u);
    __syncthreads();
    find_bin(hist, 8, KCAND, segsum, &sh_bin, &sh_before);
    unsigned P1 = sh_bin, cb1 = sh_before;
    __syncthreads();

    // pass 2: bits [20:10]
    for (int i = tid; i < 2048; i += 256) hist[i] = 0;
    __syncthreads();
    for (int n = tid; n < NMEM; n += 256) {
        unsigned u = flipf(dr[n]);
        if ((u >> 21) == P1) atomicAdd(&hist[(u >> 10) & 0x7FFu], 1u);
    }
    __syncthreads();
    find_bin(hist, 8, KCAND - cb1, segsum, &sh_bin, &sh_before);
    unsigned P2 = sh_bin, cb2 = cb1 + sh_before;
    __syncthreads();

    // pass 3: bits [9:0]
    for (int i = tid; i < 2048; i += 256) hist[i] = 0;
    __syncthreads();
    unsigned pfx = (P1 << 11) | P2;
    for (int n = tid; n < NMEM; n += 256) {
        unsigned u = flipf(dr[n]);
        if ((u >> 10) == pfx) atomicAdd(&hist[u & 0x3FFu], 1u);
    }
    __syncthreads();
    find_bin(hist, 4, KCAND - cb2, segsum, &sh_bin, &sh_before);
    unsigned T = (pfx << 10) | sh_bin;
    __syncthreads();

    // collect candidate indices
    if (tid == 0) { cnt_lt = 0; cnt_eq = 0; }
    __syncthreads();
    for (int n = tid; n < NMEM; n += 256) {
        unsigned u = flipf(dr[n]);
        if (u < T) { unsigned p = atomicAdd(&cnt_lt, 1u); sel[p] = n; }
        else if (u == T) { unsigned p = atomicAdd(&cnt_eq, 1u); if (p < 256) eqbuf[p] = n; }
    }
    __syncthreads();
    if (tid == 0) {
        int need = KCAND - (int)cnt_lt;
        int m = (int)cnt_eq; if (m > 256) m = 256;
        for (int k = 0; k < need; ++k) {
            int best = 0x7FFFFFFF, bi = 0;
            for (int i = 0; i < m; ++i) if (eqbuf[i] < best) { best = eqbuf[i]; bi = i; }
            eqbuf[bi] = 0x7FFFFFFF;
            sel[(int)cnt_lt + k] = best;
        }
    }
    __syncthreads();

    // exact f32 refine: 2 threads per candidate, 256 dims each
    int a = actions[b * NSTEPS + step];
    {
        int c = tid >> 1, h = tid & 1;
        const float* krow = keys + ((size_t)a * NMEM + sel[c]) * DIM + h * 256;
        const float* qp = qs + h * 256;
        float s = 0.f;
        #pragma unroll 8
        for (int i = 0; i < 256; i += 4) {
            float4 kv = *(const float4*)(krow + i);
            s = fmaf(kv.x, qp[i+0], s);
            s = fmaf(kv.y, qp[i+1], s);
            s = fmaf(kv.z, qp[i+2], s);
            s = fmaf(kv.w, qp[i+3], s);
        }
        part[tid] = s;
    }
    __syncthreads();
    float qnb = qn[b];
    if (tid < KCAND) {
        float dot = part[2 * tid] + part[2 * tid + 1];
        dsh[tid] = qnb + kn[a * NMEM + sel[tid]] - 2.0f * dot;
    }
    __syncthreads();
    if (tid < KCAND) {
        float di = dsh[tid]; int ni = sel[tid];
        int rank = 0;
        for (int j = 0; j < KCAND; ++j) {
            float dj = dsh[j];
            rank += (dj < di || (dj == di && sel[j] < ni)) ? 1 : 0;
        }
        if (rank < KNB) { wsel[rank] = 1.0f / (di + KDELTA); isel[rank] = ni; }
    }
    __syncthreads();
    if (tid == 0) {
        float ssum = 0.f;
        for (int i = 0; i < KNB; ++i) ssum += wsel[i];
        wsum_sh = ssum;
    }
    __syncthreads();
    if (tid < KNB) {
        w_out[b * KNB + tid] = wsel[tid] / wsum_sh;
        idx_out[b * KNB + tid] = isel[tid];
    }
}

// ---------- fused gather + next-qn + 3-layer MLP ----------
__global__ __launch_bounds__(256)
void gp_kernel(const float* __restrict__ vals, const int* __restrict__ idx,
               const float* __restrict__ w, const int* __restrict__ actions, int step,
               float* __restrict__ emb_out, float* __restrict__ qn_out,
               const float* __restrict__ w1, const float* __restrict__ b1,
               const float* __restrict__ w2, const float* __restrict__ b2,
               const float* __restrict__ w3, const float* __restrict__ b3,
               float* __restrict__ out) {
    int b = blockIdx.x, tid = threadIdx.x;
    int a = actions[b * NSTEPS + step];
    __shared__ float wl[KNB];
    __shared__ int il[KNB];
    __shared__ float red[256];
    __shared__ float xs[DIM];
    __shared__ float h1[H1N];
    __shared__ float h2[H2N];
    if (tid < KNB) { wl[tid] = w[b * KNB + tid]; il[tid] = idx[b * KNB + tid]; }
    __syncthreads();
    const float* va = vals + (size_t)a * NMEM * DIM;
    float acc0 = 0.f, acc1 = 0.f;
    for (int k = 0; k < KNB; ++k) {
        const float* vr = va + (size_t)il[k] * DIM;
        acc0 = fmaf(wl[k], vr[tid], acc0);
        acc1 = fmaf(wl[k], vr[tid + 256], acc1);
    }
    emb_out[b * DIM + tid] = acc0;
    emb_out[b * DIM + tid + 256] = acc1;
    xs[tid] = acc0; xs[tid + 256] = acc1;
    red[tid] = acc0 * acc0 + acc1 * acc1;
    __syncthreads();
    for (int s = 128; s > 0; s >>= 1) { if (tid < s) red[tid] += red[tid + s]; __syncthreads(); }
    if (tid == 0) qn_out[b] = red[0];
    // MLP
    float acc = b1[tid];
    #pragma unroll 8
    for (int d = 0; d < DIM; ++d) acc = fmaf(xs[d], w1[d * H1N + tid], acc);
    h1[tid] = acc > 0.f ? acc : expm1f(acc);
    __syncthreads();
    if (tid < H2N) {
        float a2 = b2[tid];
        #pragma unroll 8
        for (int d = 0; d < H1N; ++d) a2 = fmaf(h1[d], w2[d * H2N + tid], a2);
        h2[tid] = a2 > 0.f ? a2 : expm1f(a2);
    }
    __syncthreads();
    if (tid < 5) {
        float p = b3[tid];
        for (int d = 0; d < H2N; ++d) p = fmaf(h2[d], w3[d * 5 + tid], p);
        float o = p;
        if (tid == 1) o = 1.0f / (1.0f + expf(-p));
        out[b * (6 * 5) + (step + 1) * 5 + tid] = o;
    }
}

// ---------- standalone MLP for step 0 ----------
__global__ __launch_bounds__(256)
void predict_kernel(const float* __restrict__ emb, const float* __restrict__ w1,
                    const float* __restrict__ b1, const float* __restrict__ w2,
                    const float* __restrict__ b2, const float* __restrict__ w3,
                    const float* __restrict__ b3, float* __restrict__ out, int step) {
    int b = blockIdx.x, tid = threadIdx.x;
    __shared__ float xs[DIM];
    __shared__ float h1[H1N];
    __shared__ float h2[H2N];
    xs[tid] = emb[(size_t)b * DIM + tid];
    xs[tid + 256] = emb[(size_t)b * DIM + tid + 256];
    __syncthreads();
    float acc = b1[tid];
    #pragma unroll 8
    for (int d = 0; d < DIM; ++d) acc = fmaf(xs[d], w1[d * H1N + tid], acc);
    h1[tid] = acc > 0.f ? acc : expm1f(acc);
    __syncthreads();
    if (tid < H2N) {
        float a2 = b2[tid];
        #pragma unroll 8
        for (int d = 0; d < H1N; ++d) a2 = fmaf(h1[d], w2[d * H2N + tid], a2);
        h2[tid] = a2 > 0.f ? a2 : expm1f(a2);
    }
    __syncthreads();
    if (tid < 5) {
        float p = b3[tid];
        for (int d = 0; d < H2N; ++d) p = fmaf(h2[d], w3[d * 5 + tid], p);
        float o = p;
        if (tid == 1) o = 1.0f / (1.0f + expf(-p));
        out[b * (6 * 5) + step * 5 + tid] = o;
    }
}

extern "C" void kernel_launch(void* const* d_in, const int* in_sizes, int n_in,
                              void* d_out, int out_size, void* d_ws, size_t ws_size,
                              hipStream_t stream) {
    const float* x        = (const float*)d_in[0];
    const int*   actions  = (const int*)d_in[1];
    const float* mem_keys = (const float*)d_in[2];
    const float* mem_vals = (const float*)d_in[3];
    const float* w1 = (const float*)d_in[4];
    const float* b1 = (const float*)d_in[5];
    const float* w2 = (const float*)d_in[6];
    const float* b2 = (const float*)d_in[7];
    const float* w3 = (const float*)d_in[8];
    const float* b3 = (const float*)d_in[9];
    float* out = (float*)d_out;

    float* ws   = (float*)d_ws;
    float* kn   = ws;                            // 75008
    float* qnA  = kn + 75008;                    // 256
    float* qnB  = qnA + 256;                     // 256
    float* embA = qnB + 256;                     // 131072
    float* embB = embA + 131072;                 // 131072
    int*   perm = (int*)(embB + 131072);         // 5*768
    int*   cntb = perm + NSTEPS * NACT * BATCH;  // 5*4 (padded)
    int*   idxb = cntb + 32;                     // 12800
    float* wb   = (float*)(idxb + 12800);        // 12800
    float* distb = wb + 12800;                   // 6,400,000  (total ~27 MB)

    rownorm_kernel<<<dim3((NACT * NMEM + 3) / 4), dim3(256), 0, stream>>>(mem_keys, kn, NACT * NMEM);
    rownorm_kernel<<<dim3((BATCH + 3) / 4), dim3(256), 0, stream>>>(x, qnA, BATCH);
    predict_kernel<<<dim3(BATCH), dim3(256), 0, stream>>>(x, w1, b1, w2, b2, w3, b3, out, 0);
    group_all_kernel<<<dim3(NSTEPS), dim3(256), 0, stream>>>(actions, perm, cntb);

    const float* cur = x;
    float* qncur = qnA;
    for (int j = 0; j < NSTEPS; ++j) {
        dist_kernel<<<dim3(NACT * 2, (NMEM + TN - 1) / TN), dim3(256), 0, stream>>>(
            cur, mem_keys, kn, perm + j * NACT * BATCH, cntb + j * 4, distb);
        select_kernel<<<dim3(BATCH), dim3(256), 0, stream>>>(
            distb, cur, mem_keys, kn, qncur, actions, j, idxb, wb);
        float* enext  = (j & 1) ? embB : embA;
        float* qnnext = (j & 1) ? qnA  : qnB;
        gp_kernel<<<dim3(BATCH), dim3(256), 0, stream>>>(
            mem_vals, idxb, wb, actions, j, enext, qnnext, w1, b1, w2, b2, w3, b3, out);
        cur = enext; qncur = qnnext;
    }
}

// Round 6
// 1160.921 us; speedup vs baseline: 1.7208x; 1.1682x over previous
//
#include <hip/hip_runtime.h>

#define BATCH 256
#define DIM 512
#define NACT 3
#define NMEM 25000
#define KNB 50
#define H1N 256
#define H2N 128
#define NSTEPS 5
#define KDELTA 0.001f

#define TB 128
#define TN 128
#define BK 64

#define NF4 (NMEM / 4)     // 6250 float4 per dist row
#define CAP 2048           // candidate buffer cap

typedef __attribute__((ext_vector_type(8))) short short8;
typedef __attribute__((ext_vector_type(4))) float f32x4;

// ---------- row squared-norms (one wave per row) ----------
__global__ __launch_bounds__(256)
void rownorm_kernel(const float* __restrict__ rows, float* __restrict__ out, int nrows) {
    int wave = threadIdx.x >> 6, lane = threadIdx.x & 63;
    int r = blockIdx.x * 4 + wave;
    if (r >= nrows) return;
    const float* p = rows + (size_t)r * DIM;
    float4 v0 = *(const float4*)(p + lane * 8);
    float4 v1 = *(const float4*)(p + lane * 8 + 4);
    float s = v0.x*v0.x + v0.y*v0.y + v0.z*v0.z + v0.w*v0.w
            + v1.x*v1.x + v1.y*v1.y + v1.z*v1.z + v1.w*v1.w;
    for (int off = 32; off; off >>= 1) s += __shfl_down(s, off);
    if (lane == 0) out[r] = s;
}

// ---------- group batch rows by action, all steps in one launch ----------
__global__ __launch_bounds__(256)
void group_all_kernel(const int* __restrict__ actions,
                      int* __restrict__ perm, int* __restrict__ cnt) {
    int step = blockIdx.x;
    __shared__ int lcnt[NACT];
    __shared__ int lperm[NACT * BATCH];
    int tid = threadIdx.x;
    if (tid < NACT) lcnt[tid] = 0;
    __syncthreads();
    int a = actions[tid * NSTEPS + step];
    int pos = atomicAdd(&lcnt[a], 1);
    lperm[a * BATCH + pos] = tid;
    __syncthreads();
    if (tid < NACT) cnt[step * 4 + tid] = lcnt[tid];
    for (int aa = 0; aa < NACT; ++aa) {
        int c = lcnt[aa];
        int f = (c > 0) ? lperm[aa * BATCH] : 0;
        for (int i = c + tid; i < BATCH; i += 256) lperm[aa * BATCH + i] = f;
    }
    __syncthreads();
    for (int i = tid; i < NACT * BATCH; i += 256)
        perm[step * NACT * BATCH + i] = lperm[i];
}

__device__ __forceinline__ unsigned short bf16rn(float f) {
    unsigned u = __float_as_uint(f);
    u += 0x7FFFu + ((u >> 16) & 1u);
    return (unsigned short)(u >> 16);
}

// ---------- approx distance GEMM: single-pass bf16 MFMA, 128x128 tile ----------
__global__ __launch_bounds__(256)
void dist_kernel(const float* __restrict__ emb, const float* __restrict__ keys,
                 const float* __restrict__ kn, const int* __restrict__ perm,
                 const int* __restrict__ cnt, float* __restrict__ dist) {
    int a = blockIdx.x >> 1;
    int tb0 = (blockIdx.x & 1) * TB;
    int c = cnt[a];
    if (tb0 >= c) return;
    int n0 = blockIdx.y * TN;

    __shared__ __align__(16) unsigned short Qh[TB][BK];
    __shared__ __align__(16) unsigned short Kh[TN][BK];
    __shared__ int rows[TB];

    int tid = threadIdx.x;
    if (tid < TB) {
        int i = tb0 + tid;
        rows[tid] = perm[a * BATCH + (i < c ? i : 0)];
    }
    __syncthreads();

    int lane = tid & 63, wave = tid >> 6;
    int wm = wave >> 1, wn = wave & 1;

    f32x4 acc[4][4] = {};

    int sr = tid >> 1, sc = (tid & 1) * 32;
    int swz = (sr & 7) * 8;
    const float* keysA = keys + (size_t)a * NMEM * DIM;
    bool kvalid = (n0 + sr) < NMEM;
    const float* qsrc = emb + (size_t)rows[sr] * DIM + sc;
    const float* ksrc = keysA + (size_t)(n0 + sr) * DIM + sc;

    for (int d0 = 0; d0 < DIM; d0 += BK) {
        #pragma unroll
        for (int j = 0; j < 4; ++j) {
            float4 v0 = *(const float4*)(qsrc + d0 + j * 8);
            float4 v1 = *(const float4*)(qsrc + d0 + j * 8 + 4);
            float f[8] = {v0.x, v0.y, v0.z, v0.w, v1.x, v1.y, v1.z, v1.w};
            short8 hv;
            #pragma unroll
            for (int i = 0; i < 8; ++i) hv[i] = (short)bf16rn(f[i]);
            *(short8*)&Qh[sr][(sc + j * 8) ^ swz] = hv;
        }
        #pragma unroll
        for (int j = 0; j < 4; ++j) {
            float4 v0 = kvalid ? *(const float4*)(ksrc + d0 + j * 8)
                               : make_float4(0.f, 0.f, 0.f, 0.f);
            float4 v1 = kvalid ? *(const float4*)(ksrc + d0 + j * 8 + 4)
                               : make_float4(0.f, 0.f, 0.f, 0.f);
            float f[8] = {v0.x, v0.y, v0.z, v0.w, v1.x, v1.y, v1.z, v1.w};
            short8 hv;
            #pragma unroll
            for (int i = 0; i < 8; ++i) hv[i] = (short)bf16rn(f[i]);
            *(short8*)&Kh[sr][(sc + j * 8) ^ swz] = hv;
        }
        __syncthreads();
        #pragma unroll
        for (int kk = 0; kk < BK; kk += 32) {
            int kcol = kk + (lane >> 4) * 8;
            short8 av[4], bv[4];
            #pragma unroll
            for (int mf = 0; mf < 4; ++mf) {
                int m = wm * 64 + mf * 16 + (lane & 15);
                av[mf] = *(const short8*)&Qh[m][kcol ^ ((m & 7) * 8)];
            }
            #pragma unroll
            for (int nf = 0; nf < 4; ++nf) {
                int n = wn * 64 + nf * 16 + (lane & 15);
                bv[nf] = *(const short8*)&Kh[n][kcol ^ ((n & 7) * 8)];
            }
            #pragma unroll
            for (int mf = 0; mf < 4; ++mf)
                #pragma unroll
                for (int nf = 0; nf < 4; ++nf)
                    acc[mf][nf] = __builtin_amdgcn_mfma_f32_16x16x32_bf16(av[mf], bv[nf], acc[mf][nf], 0, 0, 0);
        }
        __syncthreads();
    }

    #pragma unroll
    for (int nf = 0; nf < 4; ++nf) {
        int n = n0 + wn * 64 + nf * 16 + (lane & 15);
        if (n >= NMEM) continue;
        float knv = kn[a * NMEM + n];
        #pragma unroll
        for (int mf = 0; mf < 4; ++mf) {
            #pragma unroll
            for (int r = 0; r < 4; ++r) {
                int m = wm * 64 + mf * 16 + (lane >> 4) * 4 + r;
                int b = rows[m];
                dist[(size_t)b * NMEM + n] = knv - 2.0f * acc[mf][nf][r];
            }
        }
    }
}

// ---------- select: stats threshold -> candidate collect -> exact f32 refine ----------
__global__ __launch_bounds__(1024)
void select_kernel(const float* __restrict__ dist, const float* __restrict__ emb,
                   const float* __restrict__ keys, const float* __restrict__ kn,
                   const float* __restrict__ qn, const int* __restrict__ actions,
                   int step, int* __restrict__ idx_out, float* __restrict__ w_out) {
    __shared__ float qs[DIM];
    __shared__ float wsum16[16], wsq16[16];
    __shared__ float Tsh, stdsh;
    __shared__ unsigned cntS;
    __shared__ int candb[CAP];
    __shared__ float dex[CAP];
    __shared__ float wsel[KNB];
    __shared__ int   isel[KNB];
    __shared__ float wsumS;

    int b = blockIdx.x, tid = threadIdx.x;
    int lane = tid & 63, wid = tid >> 6;
    const float4* d4 = (const float4*)(dist + (size_t)b * NMEM);

    // load q row
    if (tid < 128) *(float4*)&qs[tid * 4] = *(const float4*)(emb + (size_t)b * DIM + tid * 4);

    // ---- phase 1: mean/std ----
    float s = 0.f, sq = 0.f;
    for (int i = tid; i < NF4; i += 1024) {
        float4 v = d4[i];
        s  += v.x + v.y + v.z + v.w;
        sq += v.x*v.x + v.y*v.y + v.z*v.z + v.w*v.w;
    }
    #pragma unroll
    for (int m = 32; m; m >>= 1) { s += __shfl_xor(s, m); sq += __shfl_xor(sq, m); }
    if (lane == 0) { wsum16[wid] = s; wsq16[wid] = sq; }
    __syncthreads();
    if (tid == 0) {
        float S = 0.f, Q = 0.f;
        for (int i = 0; i < 16; ++i) { S += wsum16[i]; Q += wsq16[i]; }
        float mean = S / (float)NMEM;
        float var = Q / (float)NMEM - mean * mean;
        float sd = sqrtf(fmaxf(var, 0.f));
        stdsh = sd;
        Tsh = mean - 2.45f * sd;
    }
    __syncthreads();

    // ---- phase 2: collect all d < T (widen if under 128) ----
    for (int it = 0; it < 8; ++it) {
        if (tid == 0) cntS = 0;
        __syncthreads();
        float T = Tsh;
        for (int i = tid; i < NF4; i += 1024) {
            float4 v = d4[i];
            int n = i * 4;
            if (v.x < T) { unsigned p = atomicAdd(&cntS, 1u); if (p < CAP) candb[p] = n; }
            if (v.y < T) { unsigned p = atomicAdd(&cntS, 1u); if (p < CAP) candb[p] = n + 1; }
            if (v.z < T) { unsigned p = atomicAdd(&cntS, 1u); if (p < CAP) candb[p] = n + 2; }
            if (v.w < T) { unsigned p = atomicAdd(&cntS, 1u); if (p < CAP) candb[p] = n + 3; }
        }
        __syncthreads();
        if (cntS >= 128) break;
        if (tid == 0) Tsh += 0.6f * stdsh;
        __syncthreads();
    }
    int C = (int)cntS; if (C > CAP) C = CAP;

    // ---- phase 3: exact f32 distances for candidates (8 threads/cand) ----
    int a = actions[b * NSTEPS + step];
    float qnb = qn[b];
    const float* keysA = keys + (size_t)a * NMEM * DIM;
    int cslot = tid >> 3, sub = tid & 7;
    int sweeps = (C + 127) >> 7;
    for (int sw = 0; sw < sweeps; ++sw) {
        int ci = (sw << 7) + cslot;
        float dot = 0.f;
        int n = 0;
        if (ci < C) {
            n = candb[ci];
            const float* kr = keysA + (size_t)n * DIM + sub * 64;
            const float* qp = qs + sub * 64;
            #pragma unroll
            for (int i = 0; i < 64; i += 4) {
                float4 kv = *(const float4*)(kr + i);
                dot = fmaf(kv.x, qp[i+0], dot);
                dot = fmaf(kv.y, qp[i+1], dot);
                dot = fmaf(kv.z, qp[i+2], dot);
                dot = fmaf(kv.w, qp[i+3], dot);
            }
        }
        dot += __shfl_xor(dot, 1);
        dot += __shfl_xor(dot, 2);
        dot += __shfl_xor(dot, 4);
        if (ci < C && sub == 0)
            dex[ci] = qnb + kn[a * NMEM + n] - 2.0f * dot;
    }
    __syncthreads();

    // ---- phase 4: exact (d, idx) rank; top-50 ----
    for (int ci = tid; ci < C; ci += 1024) {
        float di = dex[ci]; int ni = candb[ci];
        int rank = 0;
        for (int j = 0; j < C; ++j) {
            float dj = dex[j];
            rank += (dj < di || (dj == di && candb[j] < ni)) ? 1 : 0;
        }
        if (rank < KNB) { wsel[rank] = 1.0f / (di + KDELTA); isel[rank] = ni; }
    }
    __syncthreads();
    if (tid == 0) {
        float ssum = 0.f;
        for (int i = 0; i < KNB; ++i) ssum += wsel[i];
        wsumS = ssum;
    }
    __syncthreads();
    if (tid < KNB) {
        w_out[b * KNB + tid] = wsel[tid] / wsumS;
        idx_out[b * KNB + tid] = isel[tid];
    }
}

// ---------- fused gather + next-qn + 3-layer MLP ----------
__global__ __launch_bounds__(256)
void gp_kernel(const float* __restrict__ vals, const int* __restrict__ idx,
               const float* __restrict__ w, const int* __restrict__ actions, int step,
               float* __restrict__ emb_out, float* __restrict__ qn_out,
               const float* __restrict__ w1, const float* __restrict__ b1,
               const float* __restrict__ w2, const float* __restrict__ b2,
               const float* __restrict__ w3, const float* __restrict__ b3,
               float* __restrict__ out) {
    int b = blockIdx.x, tid = threadIdx.x;
    int a = actions[b * NSTEPS + step];
    __shared__ float wl[KNB];
    __shared__ int il[KNB];
    __shared__ float red[256];
    __shared__ float xs[DIM];
    __shared__ float h1[H1N];
    __shared__ float h2[H2N];
    if (tid < KNB) { wl[tid] = w[b * KNB + tid]; il[tid] = idx[b * KNB + tid]; }
    __syncthreads();
    const float* va = vals + (size_t)a * NMEM * DIM;
    float acc0 = 0.f, acc1 = 0.f;
    for (int k = 0; k < KNB; ++k) {
        const float* vr = va + (size_t)il[k] * DIM;
        acc0 = fmaf(wl[k], vr[tid], acc0);
        acc1 = fmaf(wl[k], vr[tid + 256], acc1);
    }
    emb_out[b * DIM + tid] = acc0;
    emb_out[b * DIM + tid + 256] = acc1;
    xs[tid] = acc0; xs[tid + 256] = acc1;
    red[tid] = acc0 * acc0 + acc1 * acc1;
    __syncthreads();
    for (int s = 128; s > 0; s >>= 1) { if (tid < s) red[tid] += red[tid + s]; __syncthreads(); }
    if (tid == 0) qn_out[b] = red[0];
    float acc = b1[tid];
    #pragma unroll 8
    for (int d = 0; d < DIM; ++d) acc = fmaf(xs[d], w1[d * H1N + tid], acc);
    h1[tid] = acc > 0.f ? acc : expm1f(acc);
    __syncthreads();
    if (tid < H2N) {
        float a2 = b2[tid];
        #pragma unroll 8
        for (int d = 0; d < H1N; ++d) a2 = fmaf(h1[d], w2[d * H2N + tid], a2);
        h2[tid] = a2 > 0.f ? a2 : expm1f(a2);
    }
    __syncthreads();
    if (tid < 5) {
        float p = b3[tid];
        for (int d = 0; d < H2N; ++d) p = fmaf(h2[d], w3[d * 5 + tid], p);
        float o = p;
        if (tid == 1) o = 1.0f / (1.0f + expf(-p));
        out[b * (6 * 5) + (step + 1) * 5 + tid] = o;
    }
}

// ---------- standalone MLP for step 0 ----------
__global__ __launch_bounds__(256)
void predict_kernel(const float* __restrict__ emb, const float* __restrict__ w1,
                    const float* __restrict__ b1, const float* __restrict__ w2,
                    const float* __restrict__ b2, const float* __restrict__ w3,
                    const float* __restrict__ b3, float* __restrict__ out, int step) {
    int b = blockIdx.x, tid = threadIdx.x;
    __shared__ float xs[DIM];
    __shared__ float h1[H1N];
    __shared__ float h2[H2N];
    xs[tid] = emb[(size_t)b * DIM + tid];
    xs[tid + 256] = emb[(size_t)b * DIM + tid + 256];
    __syncthreads();
    float acc = b1[tid];
    #pragma unroll 8
    for (int d = 0; d < DIM; ++d) acc = fmaf(xs[d], w1[d * H1N + tid], acc);
    h1[tid] = acc > 0.f ? acc : expm1f(acc);
    __syncthreads();
    if (tid < H2N) {
        float a2 = b2[tid];
        #pragma unroll 8
        for (int d = 0; d < H1N; ++d) a2 = fmaf(h1[d], w2[d * H2N + tid], a2);
        h2[tid] = a2 > 0.f ? a2 : expm1f(a2);
    }
    __syncthreads();
    if (tid < 5) {
        float p = b3[tid];
        for (int d = 0; d < H2N; ++d) p = fmaf(h2[d], w3[d * 5 + tid], p);
        float o = p;
        if (tid == 1) o = 1.0f / (1.0f + expf(-p));
        out[b * (6 * 5) + step * 5 + tid] = o;
    }
}

extern "C" void kernel_launch(void* const* d_in, const int* in_sizes, int n_in,
                              void* d_out, int out_size, void* d_ws, size_t ws_size,
                              hipStream_t stream) {
    const float* x        = (const float*)d_in[0];
    const int*   actions  = (const int*)d_in[1];
    const float* mem_keys = (const float*)d_in[2];
    const float* mem_vals = (const float*)d_in[3];
    const float* w1 = (const float*)d_in[4];
    const float* b1 = (const float*)d_in[5];
    const float* w2 = (const float*)d_in[6];
    const float* b2 = (const float*)d_in[7];
    const float* w3 = (const float*)d_in[8];
    const float* b3 = (const float*)d_in[9];
    float* out = (float*)d_out;

    float* ws   = (float*)d_ws;
    float* kn   = ws;                            // 75008
    float* qnA  = kn + 75008;                    // 256
    float* qnB  = qnA + 256;                     // 256
    float* embA = qnB + 256;                     // 131072
    float* embB = embA + 131072;                 // 131072
    int*   perm = (int*)(embB + 131072);         // 5*768
    int*   cntb = perm + NSTEPS * NACT * BATCH;  // 5*4 (padded)
    int*   idxb = cntb + 32;                     // 12800
    float* wb   = (float*)(idxb + 12800);        // 12800
    float* distb = wb + 12800;                   // 6,400,000  (total ~27 MB)

    rownorm_kernel<<<dim3((NACT * NMEM + 3) / 4), dim3(256), 0, stream>>>(mem_keys, kn, NACT * NMEM);
    rownorm_kernel<<<dim3((BATCH + 3) / 4), dim3(256), 0, stream>>>(x, qnA, BATCH);
    predict_kernel<<<dim3(BATCH), dim3(256), 0, stream>>>(x, w1, b1, w2, b2, w3, b3, out, 0);
    group_all_kernel<<<dim3(NSTEPS), dim3(256), 0, stream>>>(actions, perm, cntb);

    const float* cur = x;
    float* qncur = qnA;
    for (int j = 0; j < NSTEPS; ++j) {
        dist_kernel<<<dim3(NACT * 2, (NMEM + TN - 1) / TN), dim3(256), 0, stream>>>(
            cur, mem_keys, kn, perm + j * NACT * BATCH, cntb + j * 4, distb);
        select_kernel<<<dim3(BATCH), dim3(1024), 0, stream>>>(
            distb, cur, mem_keys, kn, qncur, actions, j, idxb, wb);
        float* enext  = (j & 1) ? embB : embA;
        float* qnnext = (j & 1) ? qnA  : qnB;
        gp_kernel<<<dim3(BATCH), dim3(256), 0, stream>>>(
            mem_vals, idxb, wb, actions, j, enext, qnnext, w1, b1, w2, b2, w3, b3, out);
        cur = enext; qncur = qnnext;
    }
}

// Round 7
// 878.284 us; speedup vs baseline: 2.2746x; 1.3218x over previous
//
#include <hip/hip_runtime.h>

#define BATCH 256
#define DIM 512
#define NACT 3
#define NMEM 25000
#define KNB 50
#define H1N 256
#define H2N 128
#define NSTEPS 5
#define KDELTA 0.001f

#define TB 128
#define TN 128
#define BK 64

#define CAP 2048           // candidate buffer cap

typedef __attribute__((ext_vector_type(8))) short short8;
typedef __attribute__((ext_vector_type(4))) float f32x4;

__device__ __forceinline__ unsigned short bf16rn(float f) {
    unsigned u = __float_as_uint(f);
    u += 0x7FFFu + ((u >> 16) & 1u);
    return (unsigned short)(u >> 16);
}
__device__ __forceinline__ float blo(unsigned u) { return __uint_as_float(u << 16); }
__device__ __forceinline__ float bhi(unsigned u) { return __uint_as_float(u & 0xFFFF0000u); }

// ---------- prep keys: f32 -> bf16 copy + row squared-norms (one wave per row) ----------
__global__ __launch_bounds__(256)
void prep_keys_kernel(const float* __restrict__ rows, unsigned short* __restrict__ kb,
                      float* __restrict__ kn, int nrows) {
    int wave = threadIdx.x >> 6, lane = threadIdx.x & 63;
    int r = blockIdx.x * 4 + wave;
    if (r >= nrows) return;
    const float* p = rows + (size_t)r * DIM;
    float4 v0 = *(const float4*)(p + lane * 8);
    float4 v1 = *(const float4*)(p + lane * 8 + 4);
    float f[8] = {v0.x, v0.y, v0.z, v0.w, v1.x, v1.y, v1.z, v1.w};
    short8 hv;
    float s = 0.f;
    #pragma unroll
    for (int i = 0; i < 8; ++i) { hv[i] = (short)bf16rn(f[i]); s += f[i] * f[i]; }
    *(short8*)(kb + (size_t)r * DIM + lane * 8) = hv;
    for (int off = 32; off; off >>= 1) s += __shfl_down(s, off);
    if (lane == 0) kn[r] = s;
}

// ---------- group batch rows by action, all steps in one launch ----------
__global__ __launch_bounds__(256)
void group_all_kernel(const int* __restrict__ actions,
                      int* __restrict__ perm, int* __restrict__ cnt) {
    int step = blockIdx.x;
    __shared__ int lcnt[NACT];
    __shared__ int lperm[NACT * BATCH];
    int tid = threadIdx.x;
    if (tid < NACT) lcnt[tid] = 0;
    __syncthreads();
    int a = actions[tid * NSTEPS + step];
    int pos = atomicAdd(&lcnt[a], 1);
    lperm[a * BATCH + pos] = tid;
    __syncthreads();
    if (tid < NACT) cnt[step * 4 + tid] = lcnt[tid];
    for (int aa = 0; aa < NACT; ++aa) {
        int c = lcnt[aa];
        int f = (c > 0) ? lperm[aa * BATCH] : 0;
        for (int i = c + tid; i < BATCH; i += 256) lperm[aa * BATCH + i] = f;
    }
    __syncthreads();
    for (int i = tid; i < NACT * BATCH; i += 256)
        perm[step * NACT * BATCH + i] = lperm[i];
}

// ---------- approx distance GEMM: bf16 MFMA, 128x128 tile, prefetched staging ----------
__global__ __launch_bounds__(256)
void dist_kernel(const unsigned short* __restrict__ eb, const unsigned short* __restrict__ kb,
                 const float* __restrict__ kn, const int* __restrict__ perm,
                 const int* __restrict__ cnt, unsigned short* __restrict__ dist) {
    int a = blockIdx.x >> 1;
    int tb0 = (blockIdx.x & 1) * TB;
    int c = cnt[a];
    if (tb0 >= c) return;
    int n0 = blockIdx.y * TN;

    __shared__ __align__(16) unsigned short Qh[TB][BK];
    __shared__ __align__(16) unsigned short Kh[TN][BK];
    __shared__ int rows[TB];

    int tid = threadIdx.x;
    if (tid < TB) {
        int i = tb0 + tid;
        rows[tid] = perm[a * BATCH + (i < c ? i : 0)];
    }
    __syncthreads();

    int lane = tid & 63, wave = tid >> 6;
    int wm = wave >> 1, wn = wave & 1;

    f32x4 acc[4][4] = {};

    int sr = tid >> 1, sc = (tid & 1) * 32;
    int swz = (sr & 7) * 8;
    const unsigned short* kbA = kb + (size_t)a * NMEM * DIM;
    int krow = (n0 + sr < NMEM) ? (n0 + sr) : (NMEM - 1);
    const unsigned short* qsrc = eb + (size_t)rows[sr] * DIM + sc;
    const unsigned short* ksrc = kbA + (size_t)krow * DIM + sc;

    short8 qv[4], kv[4];
    #pragma unroll
    for (int j = 0; j < 4; ++j) {
        qv[j] = *(const short8*)(qsrc + j * 8);
        kv[j] = *(const short8*)(ksrc + j * 8);
    }

    for (int d0 = 0; d0 < DIM; d0 += BK) {
        // write staged regs to LDS (swizzled)
        #pragma unroll
        for (int j = 0; j < 4; ++j) {
            *(short8*)&Qh[sr][(sc + j * 8) ^ swz] = qv[j];
            *(short8*)&Kh[sr][(sc + j * 8) ^ swz] = kv[j];
        }
        __syncthreads();
        // prefetch next chunk (latency hides under MFMA phase)
        if (d0 + BK < DIM) {
            #pragma unroll
            for (int j = 0; j < 4; ++j) {
                qv[j] = *(const short8*)(qsrc + d0 + BK + j * 8);
                kv[j] = *(const short8*)(ksrc + d0 + BK + j * 8);
            }
        }
        #pragma unroll
        for (int kk = 0; kk < BK; kk += 32) {
            int kcol = kk + (lane >> 4) * 8;
            short8 av[4], bv[4];
            #pragma unroll
            for (int mf = 0; mf < 4; ++mf) {
                int m = wm * 64 + mf * 16 + (lane & 15);
                av[mf] = *(const short8*)&Qh[m][kcol ^ ((m & 7) * 8)];
            }
            #pragma unroll
            for (int nf = 0; nf < 4; ++nf) {
                int n = wn * 64 + nf * 16 + (lane & 15);
                bv[nf] = *(const short8*)&Kh[n][kcol ^ ((n & 7) * 8)];
            }
            #pragma unroll
            for (int mf = 0; mf < 4; ++mf)
                #pragma unroll
                for (int nf = 0; nf < 4; ++nf)
                    acc[mf][nf] = __builtin_amdgcn_mfma_f32_16x16x32_bf16(av[mf], bv[nf], acc[mf][nf], 0, 0, 0);
        }
        __syncthreads();
    }

    // C/D layout: col=lane&15, row=(lane>>4)*4+reg ; bf16 store
    #pragma unroll
    for (int nf = 0; nf < 4; ++nf) {
        int n = n0 + wn * 64 + nf * 16 + (lane & 15);
        if (n >= NMEM) continue;
        float knv = kn[a * NMEM + n];
        #pragma unroll
        for (int mf = 0; mf < 4; ++mf) {
            #pragma unroll
            for (int r = 0; r < 4; ++r) {
                int m = wm * 64 + mf * 16 + (lane >> 4) * 4 + r;
                int b = rows[m];
                dist[(size_t)b * NMEM + n] = bf16rn(knv - 2.0f * acc[mf][nf][r]);
            }
        }
    }
}

// ---------- select: stats threshold -> candidate collect -> exact f32 refine ----------
__global__ __launch_bounds__(1024)
void select_kernel(const unsigned short* __restrict__ dist, const float* __restrict__ emb,
                   const float* __restrict__ keys, const float* __restrict__ kn,
                   const float* __restrict__ qn, const int* __restrict__ actions,
                   int step, int* __restrict__ idx_out, float* __restrict__ w_out) {
    __shared__ float qs[DIM];
    __shared__ float wsum16[16], wsq16[16];
    __shared__ float Tsh, stdsh;
    __shared__ unsigned cntS;
    __shared__ int candb[CAP];
    __shared__ float dex[CAP];
    __shared__ float wsel[KNB];
    __shared__ int   isel[KNB];
    __shared__ float wsumS;

    int b = blockIdx.x, tid = threadIdx.x;
    int lane = tid & 63, wid = tid >> 6;
    const uint4* d8 = (const uint4*)(dist + (size_t)b * NMEM);   // 8 bf16 per uint4

    if (tid < 128) *(float4*)&qs[tid * 4] = *(const float4*)(emb + (size_t)b * DIM + tid * 4);

    // ---- phase 1: mean/std ----
    float s = 0.f, sq = 0.f;
    for (int i = tid; i < NMEM / 8; i += 1024) {
        uint4 v = d8[i];
        float f0 = blo(v.x), f1 = bhi(v.x), f2 = blo(v.y), f3 = bhi(v.y);
        float f4 = blo(v.z), f5 = bhi(v.z), f6 = blo(v.w), f7 = bhi(v.w);
        s  += ((f0 + f1) + (f2 + f3)) + ((f4 + f5) + (f6 + f7));
        sq += ((f0*f0 + f1*f1) + (f2*f2 + f3*f3)) + ((f4*f4 + f5*f5) + (f6*f6 + f7*f7));
    }
    #pragma unroll
    for (int m = 32; m; m >>= 1) { s += __shfl_xor(s, m); sq += __shfl_xor(sq, m); }
    if (lane == 0) { wsum16[wid] = s; wsq16[wid] = sq; }
    __syncthreads();
    if (tid == 0) {
        float S = 0.f, Q = 0.f;
        for (int i = 0; i < 16; ++i) { S += wsum16[i]; Q += wsq16[i]; }
        float mean = S / (float)NMEM;
        float var = Q / (float)NMEM - mean * mean;
        float sd = sqrtf(fmaxf(var, 0.f));
        stdsh = sd;
        Tsh = mean - 2.45f * sd;
    }
    __syncthreads();

    // ---- phase 2: collect all d < T (widen if under 128) ----
    for (int it = 0; it < 8; ++it) {
        if (tid == 0) cntS = 0;
        __syncthreads();
        float T = Tsh;
        for (int i = tid; i < NMEM / 8; i += 1024) {
            uint4 v = d8[i];
            int n = i * 8;
            float f[8] = {blo(v.x), bhi(v.x), blo(v.y), bhi(v.y),
                          blo(v.z), bhi(v.z), blo(v.w), bhi(v.w)};
            #pragma unroll
            for (int k = 0; k < 8; ++k)
                if (f[k] < T) { unsigned p = atomicAdd(&cntS, 1u); if (p < CAP) candb[p] = n + k; }
        }
        __syncthreads();
        if (cntS >= 128) break;
        if (tid == 0) Tsh += 0.6f * stdsh;
        __syncthreads();
    }
    int C = (int)cntS; if (C > CAP) C = CAP;

    // ---- phase 3: exact f32 distances for candidates (8 threads/cand) ----
    int a = actions[b * NSTEPS + step];
    float qnb = qn[b];
    const float* keysA = keys + (size_t)a * NMEM * DIM;
    int cslot = tid >> 3, sub = tid & 7;
    int sweeps = (C + 127) >> 7;
    for (int sw = 0; sw < sweeps; ++sw) {
        int ci = (sw << 7) + cslot;
        float dot = 0.f;
        int n = 0;
        if (ci < C) {
            n = candb[ci];
            const float* kr = keysA + (size_t)n * DIM + sub * 64;
            const float* qp = qs + sub * 64;
            #pragma unroll
            for (int i = 0; i < 64; i += 4) {
                float4 kv = *(const float4*)(kr + i);
                dot = fmaf(kv.x, qp[i+0], dot);
                dot = fmaf(kv.y, qp[i+1], dot);
                dot = fmaf(kv.z, qp[i+2], dot);
                dot = fmaf(kv.w, qp[i+3], dot);
            }
        }
        dot += __shfl_xor(dot, 1);
        dot += __shfl_xor(dot, 2);
        dot += __shfl_xor(dot, 4);
        if (ci < C && sub == 0)
            dex[ci] = qnb + kn[a * NMEM + n] - 2.0f * dot;
    }
    __syncthreads();

    // ---- phase 4: exact (d, idx) rank; top-50 ----
    for (int ci = tid; ci < C; ci += 1024) {
        float di = dex[ci]; int ni = candb[ci];
        int rank = 0;
        for (int j = 0; j < C; ++j) {
            float dj = dex[j];
            rank += (dj < di || (dj == di && candb[j] < ni)) ? 1 : 0;
        }
        if (rank < KNB) { wsel[rank] = 1.0f / (di + KDELTA); isel[rank] = ni; }
    }
    __syncthreads();
    if (tid == 0) {
        float ssum = 0.f;
        for (int i = 0; i < KNB; ++i) ssum += wsel[i];
        wsumS = ssum;
    }
    __syncthreads();
    if (tid < KNB) {
        w_out[b * KNB + tid] = wsel[tid] / wsumS;
        idx_out[b * KNB + tid] = isel[tid];
    }
}

// ---------- fused gather + next-qn + bf16 emb + 3-layer MLP ----------
__global__ __launch_bounds__(256)
void gp_kernel(const float* __restrict__ vals, const int* __restrict__ idx,
               const float* __restrict__ w, const int* __restrict__ actions, int step,
               float* __restrict__ emb_out, unsigned short* __restrict__ eb_out,
               float* __restrict__ qn_out,
               const float* __restrict__ w1, const float* __restrict__ b1,
               const float* __restrict__ w2, const float* __restrict__ b2,
               const float* __restrict__ w3, const float* __restrict__ b3,
               float* __restrict__ out) {
    int b = blockIdx.x, tid = threadIdx.x;
    int a = actions[b * NSTEPS + step];
    __shared__ float wl[KNB];
    __shared__ int il[KNB];
    __shared__ float red[256];
    __shared__ float xs[DIM];
    __shared__ float h1[H1N];
    __shared__ float h2[H2N];
    if (tid < KNB) { wl[tid] = w[b * KNB + tid]; il[tid] = idx[b * KNB + tid]; }
    __syncthreads();
    const float* va = vals + (size_t)a * NMEM * DIM;
    float acc0 = 0.f, acc1 = 0.f;
    for (int k = 0; k < KNB; ++k) {
        const float* vr = va + (size_t)il[k] * DIM;
        acc0 = fmaf(wl[k], vr[tid], acc0);
        acc1 = fmaf(wl[k], vr[tid + 256], acc1);
    }
    emb_out[b * DIM + tid] = acc0;
    emb_out[b * DIM + tid + 256] = acc1;
    eb_out[b * DIM + tid] = bf16rn(acc0);
    eb_out[b * DIM + tid + 256] = bf16rn(acc1);
    xs[tid] = acc0; xs[tid + 256] = acc1;
    red[tid] = acc0 * acc0 + acc1 * acc1;
    __syncthreads();
    for (int s = 128; s > 0; s >>= 1) { if (tid < s) red[tid] += red[tid + s]; __syncthreads(); }
    if (tid == 0) qn_out[b] = red[0];
    float acc = b1[tid];
    #pragma unroll 8
    for (int d = 0; d < DIM; ++d) acc = fmaf(xs[d], w1[d * H1N + tid], acc);
    h1[tid] = acc > 0.f ? acc : expm1f(acc);
    __syncthreads();
    if (tid < H2N) {
        float a2 = b2[tid];
        #pragma unroll 8
        for (int d = 0; d < H1N; ++d) a2 = fmaf(h1[d], w2[d * H2N + tid], a2);
        h2[tid] = a2 > 0.f ? a2 : expm1f(a2);
    }
    __syncthreads();
    if (tid < 5) {
        float p = b3[tid];
        for (int d = 0; d < H2N; ++d) p = fmaf(h2[d], w3[d * 5 + tid], p);
        float o = p;
        if (tid == 1) o = 1.0f / (1.0f + expf(-p));
        out[b * (6 * 5) + (step + 1) * 5 + tid] = o;
    }
}

// ---------- prep x: bf16 copy + qn ----------
__global__ __launch_bounds__(256)
void prep_x_kernel(const float* __restrict__ rows, unsigned short* __restrict__ eb,
                   float* __restrict__ qn, int nrows) {
    int wave = threadIdx.x >> 6, lane = threadIdx.x & 63;
    int r = blockIdx.x * 4 + wave;
    if (r >= nrows) return;
    const float* p = rows + (size_t)r * DIM;
    float4 v0 = *(const float4*)(p + lane * 8);
    float4 v1 = *(const float4*)(p + lane * 8 + 4);
    float f[8] = {v0.x, v0.y, v0.z, v0.w, v1.x, v1.y, v1.z, v1.w};
    short8 hv;
    float s = 0.f;
    #pragma unroll
    for (int i = 0; i < 8; ++i) { hv[i] = (short)bf16rn(f[i]); s += f[i] * f[i]; }
    *(short8*)(eb + (size_t)r * DIM + lane * 8) = hv;
    for (int off = 32; off; off >>= 1) s += __shfl_down(s, off);
    if (lane == 0) qn[r] = s;
}

// ---------- standalone MLP for step 0 ----------
__global__ __launch_bounds__(256)
void predict_kernel(const float* __restrict__ emb, const float* __restrict__ w1,
                    const float* __restrict__ b1, const float* __restrict__ w2,
                    const float* __restrict__ b2, const float* __restrict__ w3,
                    const float* __restrict__ b3, float* __restrict__ out, int step) {
    int b = blockIdx.x, tid = threadIdx.x;
    __shared__ float xs[DIM];
    __shared__ float h1[H1N];
    __shared__ float h2[H2N];
    xs[tid] = emb[(size_t)b * DIM + tid];
    xs[tid + 256] = emb[(size_t)b * DIM + tid + 256];
    __syncthreads();
    float acc = b1[tid];
    #pragma unroll 8
    for (int d = 0; d < DIM; ++d) acc = fmaf(xs[d], w1[d * H1N + tid], acc);
    h1[tid] = acc > 0.f ? acc : expm1f(acc);
    __syncthreads();
    if (tid < H2N) {
        float a2 = b2[tid];
        #pragma unroll 8
        for (int d = 0; d < H1N; ++d) a2 = fmaf(h1[d], w2[d * H2N + tid], a2);
        h2[tid] = a2 > 0.f ? a2 : expm1f(a2);
    }
    __syncthreads();
    if (tid < 5) {
        float p = b3[tid];
        for (int d = 0; d < H2N; ++d) p = fmaf(h2[d], w3[d * 5 + tid], p);
        float o = p;
        if (tid == 1) o = 1.0f / (1.0f + expf(-p));
        out[b * (6 * 5) + step * 5 + tid] = o;
    }
}

extern "C" void kernel_launch(void* const* d_in, const int* in_sizes, int n_in,
                              void* d_out, int out_size, void* d_ws, size_t ws_size,
                              hipStream_t stream) {
    const float* x        = (const float*)d_in[0];
    const int*   actions  = (const int*)d_in[1];
    const float* mem_keys = (const float*)d_in[2];
    const float* mem_vals = (const float*)d_in[3];
    const float* w1 = (const float*)d_in[4];
    const float* b1 = (const float*)d_in[5];
    const float* w2 = (const float*)d_in[6];
    const float* b2 = (const float*)d_in[7];
    const float* w3 = (const float*)d_in[8];
    const float* b3 = (const float*)d_in[9];
    float* out = (float*)d_out;

    // workspace layout (bytes; 16B-aligned blocks)
    char* W = (char*)d_ws;
    unsigned short* kb    = (unsigned short*)W;                 // 76,800,000 B
    unsigned short* distb = (unsigned short*)(W + 76800000);    // 12,800,000 B
    unsigned short* eb    = (unsigned short*)(W + 89600000);    //    262,144 B
    float* kn   = (float*)(W + 89862144);                       //    300,032 B
    float* qnb  = (float*)(W + 90162176);                       //      1,024 B
    float* emb  = (float*)(W + 90163200);                       //    524,288 B
    int*   perm = (int*)(W + 90687488);                         //     15,360 B
    int*   cntb = (int*)(W + 90702848);                         //        128 B
    int*   idxb = (int*)(W + 90702976);                         //     51,200 B
    float* wb   = (float*)(W + 90754176);                       //     51,200 B  (end ~90.8 MB)

    prep_keys_kernel<<<dim3((NACT * NMEM + 3) / 4), dim3(256), 0, stream>>>(mem_keys, kb, kn, NACT * NMEM);
    prep_x_kernel<<<dim3((BATCH + 3) / 4), dim3(256), 0, stream>>>(x, eb, qnb, BATCH);
    predict_kernel<<<dim3(BATCH), dim3(256), 0, stream>>>(x, w1, b1, w2, b2, w3, b3, out, 0);
    group_all_kernel<<<dim3(NSTEPS), dim3(256), 0, stream>>>(actions, perm, cntb);

    const float* cur = x;
    for (int j = 0; j < NSTEPS; ++j) {
        dist_kernel<<<dim3(NACT * 2, (NMEM + TN - 1) / TN), dim3(256), 0, stream>>>(
            eb, kb, kn, perm + j * NACT * BATCH, cntb + j * 4, distb);
        select_kernel<<<dim3(BATCH), dim3(1024), 0, stream>>>(
            distb, cur, mem_keys, kn, qnb, actions, j, idxb, wb);
        gp_kernel<<<dim3(BATCH), dim3(256), 0, stream>>>(
            mem_vals, idxb, wb, actions, j, emb, eb, qnb, w1, b1, w2, b2, w3, b3, out);
        cur = emb;
    }
}